// Round 11
// baseline (231.230 us; speedup 1.0000x reference)
//
#include <hip/hip_runtime.h>

// SIZE=65536 nodes, MAX_EDGES=16777216.
// out[i] = bias[i] + sum over edges e with dst[e]==i of x[src[e]]*w[e].
//
// Ledger (us): overhead ~135 | wx_lds 63 | hist2 ~25 | reduce ~8.
// R1: global fp32 atomics ~20.6 G/s -> LDS histograms.
// R10: LDS-gather wx (x fp16 in 128KB LDS): 105->67us.
// R11: int32 fixed-point ds_add_u32 (2^22) broke the LDS f32-atomic floor:
//     hist2 98 -> ~25us.
// R12: fp16 wx: 67->63us. Software prefetch collapsed (VGPR 28) -- 4th
//     failure; hipcc always sinks loads to uses.
// R13: asm depth-4 prefetch -> GPU FAULT. Post-mortem: (1) rule-18 hazard:
//     VALU addr-calc reading asm-load outputs hoisted ABOVE the waitcnt
//     ("memory" clobber doesn't order register-only ops) -> ds_read from
//     garbage register; (2) vmcnt N values assumed store positions.
// R14 (this): same pipeline, hardened per guide errata:
//     - __builtin_amdgcn_sched_barrier(0) immediately after EVERY waitcnt
//       (the only fix that works, r282; early-clobber does not).
//     - waitcnt N safe under loads-only accounting (stores only add slack):
//       steady N=16, drain 12/8/4/0. Over-wait harmless, under-wait faults.
//     Arithmetic unchanged -> absmax must stay 0.001953125.
//     Fallback on fault/regression: R12 form (230.6us).

#define NNODES  65536
#define NEDGES  16777216
#define THREADS 1024
#define NCOPIES 128                 // private output copies in ws (32 MB)
#define GROUPS  16
#define CPG     (NCOPIES / GROUPS)  // 8 copies per reduce group
#define RANGES  2
#define BINS    (NNODES / RANGES)   // 32768 bins -> 128 KB LDS hist

#define FIXSCALE   4194304.0f       // 2^22
#define FIXINV     (1.0f / 4194304.0f)

__device__ __forceinline__ int4 gld16i(const void* p) {
    int4 r;
    asm volatile("global_load_dwordx4 %0, %1, off" : "=v"(r) : "v"(p));
    return r;
}
__device__ __forceinline__ float4 gld16f(const void* p) {
    float4 r;
    asm volatile("global_load_dwordx4 %0, %1, off" : "=v"(r) : "v"(p));
    return r;
}

// ---------------- Stage P: x->LDS fp16, asm-pipelined wx (fp16 out) --------
// grid 256 x 1024, dynamic LDS = 128 KB (1 block/CU, 16 waves).
__global__ __launch_bounds__(THREADS, 4) void wx_lds_kernel(
    const float* __restrict__ x,
    const float* __restrict__ w,
    const int*   __restrict__ src,
    void*        __restrict__ wxv)
{
    extern __shared__ _Float16 xs[];   // 64K halves = 128 KB

    for (int i = threadIdx.x; i < NNODES / 4; i += THREADS) {
        float4 v = ((const float4*)x)[i];
        union { _Float16 hh[4]; short4 s4; } u;
        u.hh[0] = (_Float16)v.x; u.hh[1] = (_Float16)v.y;
        u.hh[2] = (_Float16)v.z; u.hh[3] = (_Float16)v.w;
        ((short4*)xs)[i] = u.s4;
    }
    __syncthreads();   // drains staging loads: vmcnt clean at loop entry

    const int n8 = NEDGES / 8;
    const int gs = gridDim.x * THREADS;
    const int i0 = blockIdx.x * THREADS + (int)threadIdx.x;

    if ((n8 % gs) == 0 && (n8 / gs) == 8) {
        const long  gsB = (long)gs * 32;
        const char* ps  = (const char*)src + (long)i0 * 32;
        const char* pw  = (const char*)w   + (long)i0 * 32;

#define WX_LOAD(G) \
        int4   s0_##G = gld16i(ps + (G) * gsB); \
        int4   s1_##G = gld16i(ps + (G) * gsB + 16); \
        float4 w0_##G = gld16f(pw + (G) * gsB); \
        float4 w1_##G = gld16f(pw + (G) * gsB + 16);

// Rule-18 hardened consume: waitcnt, then a full scheduling fence so NO
// dependent op (incl. pure-VALU addr calc on the asm-load outputs) can sit
// above the waitcnt. N is safe under loads-only vmcnt accounting.
#define WX_CONS(G, NWAIT) do { \
        asm volatile("s_waitcnt vmcnt(" #NWAIT ")" ::: "memory"); \
        __builtin_amdgcn_sched_barrier(0); \
        float v[8] = { \
            (float)xs[s0_##G.x] * w0_##G.x, (float)xs[s0_##G.y] * w0_##G.y, \
            (float)xs[s0_##G.z] * w0_##G.z, (float)xs[s0_##G.w] * w0_##G.w, \
            (float)xs[s1_##G.x] * w1_##G.x, (float)xs[s1_##G.y] * w1_##G.y, \
            (float)xs[s1_##G.z] * w1_##G.z, (float)xs[s1_##G.w] * w1_##G.w }; \
        union { _Float16 hh[8]; int4 p; } u; \
        _Pragma("unroll") \
        for (int k = 0; k < 8; ++k) u.hh[k] = (_Float16)v[k]; \
        ((int4*)wxv)[i0 + (G) * gs] = u.p; \
    } while (0)

        // Prologue: groups 0-3 in flight (16 loads).
        WX_LOAD(0) WX_LOAD(1) WX_LOAD(2) WX_LOAD(3)
        // Steady state: issue g(k+4), wait for g(k) (<=16 loads outstanding
        // after wait under loads-only model), consume g(k).
        WX_LOAD(4) WX_CONS(0, 16);
        WX_LOAD(5) WX_CONS(1, 16);
        WX_LOAD(6) WX_CONS(2, 16);
        WX_LOAD(7) WX_CONS(3, 16);
        // Drain.
        WX_CONS(4, 12);
        WX_CONS(5, 8);
        WX_CONS(6, 4);
        WX_CONS(7, 0);

#undef WX_LOAD
#undef WX_CONS
    } else {
        // Generic path (no asm).
        const int4*   src4 = (const int4*)src;
        const float4* wgt4 = (const float4*)w;
        for (int i = i0; i < n8; i += gs) {
            int4   s0 = src4[2 * i], s1 = src4[2 * i + 1];
            float4 w0 = wgt4[2 * i], w1 = wgt4[2 * i + 1];
            float v[8] = {
                (float)xs[s0.x] * w0.x, (float)xs[s0.y] * w0.y,
                (float)xs[s0.z] * w0.z, (float)xs[s0.w] * w0.w,
                (float)xs[s1.x] * w1.x, (float)xs[s1.y] * w1.y,
                (float)xs[s1.z] * w1.z, (float)xs[s1.w] * w1.w };
            union { _Float16 hh[8]; int4 p; } u;
            #pragma unroll
            for (int k = 0; k < 8; ++k) u.hh[k] = (_Float16)v[k];
            ((int4*)wxv)[i] = u.p;
        }
    }
}

// ---------------- Stage H: gather-free INT LDS histogram ----------------
// grid 256 (128 chunks x 2 ranges), 128 KB LDS. Blocks b, b^8 share chunk c
// and b%8 (same XCD) -> duplicate dst/wx chunk read is an L2 hit.
__global__ __launch_bounds__(THREADS, 4) void hist2_kernel(
    const int*  __restrict__ dst,
    const void* __restrict__ wxv,
    float*      __restrict__ ws,
    int B)
{
    extern __shared__ int hi[];   // BINS ints = 128 KB

    const int b = blockIdx.x;
    int r, c;
    if (B == NCOPIES) {
        r = (b >> 3) & (RANGES - 1);
        c = (b & 7) | ((b >> 4) << 3);
    } else {
        r = b & (RANGES - 1);
        c = b >> 1;
    }
    const int lo = r * BINS;

    for (int i = threadIdx.x; i < BINS; i += THREADS) hi[i] = 0;
    __syncthreads();

    const int4* dst4 = (const int4*)dst;
    const int n8     = NEDGES / 8;
    const int stride = B * THREADS;
    int g = c * THREADS + (int)threadIdx.x;

    if ((n8 % (2 * stride)) == 0 && n8 >= 2 * stride) {
        const int niter2 = n8 / (2 * stride);   // 8 when B=128
        for (int it = 0; it < niter2; ++it, g += 2 * stride) {
            const int ga = g;
            const int gb = g + stride;

            int4 dA0 = dst4[2 * ga], dA1 = dst4[2 * ga + 1];
            int4 dB0 = dst4[2 * gb], dB1 = dst4[2 * gb + 1];

            int4 pa = ((const int4*)wxv)[ga];
            int4 pb = ((const int4*)wxv)[gb];
            union { int4 p; _Float16 hh[8]; } ua, ub;
            ua.p = pa; ub.p = pb;

            float vv[16];
            #pragma unroll
            for (int k = 0; k < 8; ++k) {
                vv[k]     = (float)ua.hh[k];
                vv[8 + k] = (float)ub.hh[k];
            }

            unsigned bin[16] = {
                (unsigned)(dA0.x - lo), (unsigned)(dA0.y - lo),
                (unsigned)(dA0.z - lo), (unsigned)(dA0.w - lo),
                (unsigned)(dA1.x - lo), (unsigned)(dA1.y - lo),
                (unsigned)(dA1.z - lo), (unsigned)(dA1.w - lo),
                (unsigned)(dB0.x - lo), (unsigned)(dB0.y - lo),
                (unsigned)(dB0.z - lo), (unsigned)(dB0.w - lo),
                (unsigned)(dB1.x - lo), (unsigned)(dB1.y - lo),
                (unsigned)(dB1.z - lo), (unsigned)(dB1.w - lo) };

            #pragma unroll
            for (int k = 0; k < 16; ++k) {
                if (bin[k] < (unsigned)BINS) {
                    int iv = __float2int_rn(vv[k] * FIXSCALE);
                    atomicAdd(&hi[bin[k]], iv);
                }
            }
        }
    } else {
        for (; g < n8; g += stride) {
            int4 d0 = dst4[2 * g], d1 = dst4[2 * g + 1];
            int4 p = ((const int4*)wxv)[g];
            union { int4 p; _Float16 hh[8]; } u; u.p = p;
            float vv[8];
            #pragma unroll
            for (int k = 0; k < 8; ++k) vv[k] = (float)u.hh[k];
            unsigned bin[8] = {
                (unsigned)(d0.x - lo), (unsigned)(d0.y - lo),
                (unsigned)(d0.z - lo), (unsigned)(d0.w - lo),
                (unsigned)(d1.x - lo), (unsigned)(d1.y - lo),
                (unsigned)(d1.z - lo), (unsigned)(d1.w - lo) };
            #pragma unroll
            for (int k = 0; k < 8; ++k) {
                if (bin[k] < (unsigned)BINS) {
                    int iv = __float2int_rn(vv[k] * FIXSCALE);
                    atomicAdd(&hi[bin[k]], iv);
                }
            }
        }
    }
    __syncthreads();

    float* outc = ws + (size_t)c * NNODES + lo;
    for (int i = threadIdx.x; i < BINS; i += THREADS)
        outc[i] = (float)hi[i] * FIXINV;
}

// ---------------- Fallback Stage 1 (R6): fused gather+hist ----------------
__global__ __launch_bounds__(THREADS, 4) void hist_kernel(
    const float* __restrict__ x,
    const float* __restrict__ w,
    const int*   __restrict__ src,
    const int*   __restrict__ dst,
    float*       __restrict__ ws,
    int B)
{
    extern __shared__ float h[];   // BINS floats = 128 KB

    const int b = blockIdx.x;
    int r, c;
    if (B == NCOPIES) {
        r = (b >> 3) & (RANGES - 1);
        c = (b & 7) | ((b >> 4) << 3);
    } else {
        r = b & (RANGES - 1);
        c = b >> 1;
    }
    const int lo = r * BINS;

    for (int i = threadIdx.x; i < BINS; i += THREADS) h[i] = 0.0f;
    __syncthreads();

    const int4*   src4 = (const int4*)src;
    const int4*   dst4 = (const int4*)dst;
    const float4* wgt4 = (const float4*)w;

    const int n8     = NEDGES / 8;
    const int stride = B * THREADS;
    int g = c * THREADS + (int)threadIdx.x;

    for (; g < n8; g += stride) {
        int4   sa = src4[2 * g], sb = src4[2 * g + 1];
        int4   da = dst4[2 * g], db = dst4[2 * g + 1];
        float4 wa = wgt4[2 * g], wb = wgt4[2 * g + 1];

        int      s[8]  = { sa.x, sa.y, sa.z, sa.w, sb.x, sb.y, sb.z, sb.w };
        unsigned bin[8] = {
            (unsigned)(da.x - lo), (unsigned)(da.y - lo),
            (unsigned)(da.z - lo), (unsigned)(da.w - lo),
            (unsigned)(db.x - lo), (unsigned)(db.y - lo),
            (unsigned)(db.z - lo), (unsigned)(db.w - lo) };
        float    wv[8] = { wa.x, wa.y, wa.z, wa.w, wb.x, wb.y, wb.z, wb.w };

        float v[8];
        #pragma unroll
        for (int k = 0; k < 8; ++k) {
            v[k] = 0.0f;
            if (bin[k] < (unsigned)BINS) v[k] = x[s[k]] * wv[k];
        }
        #pragma unroll
        for (int k = 0; k < 8; ++k) {
            if (bin[k] < (unsigned)BINS) atomicAdd(&h[bin[k]], v[k]);
        }
    }
    __syncthreads();

    float* outc = ws + (size_t)c * NNODES + lo;
    for (int i = threadIdx.x; i < BINS; i += THREADS) outc[i] = h[i];
}

// ---------------- Stage 2a: tree reduce 128 -> 16 (in-place) ----------------
__global__ __launch_bounds__(256) void reduceA_kernel(float* __restrict__ ws)
{
    const int NB = NNODES / (256 * 4);
    int g  = blockIdx.x / NB;
    int jb = blockIdx.x % NB;
    int i4 = jb * 256 + (int)threadIdx.x;

    float4* w4 = (float4*)ws;
    const int stride4 = NNODES / 4;

    float4 acc = w4[(size_t)(g * CPG) * stride4 + i4];
    #pragma unroll
    for (int cc = 1; cc < CPG; ++cc) {
        float4 t = w4[(size_t)(g * CPG + cc) * stride4 + i4];
        acc.x += t.x; acc.y += t.y; acc.z += t.z; acc.w += t.w;
    }
    w4[(size_t)(g * CPG) * stride4 + i4] = acc;
}

// ---------------- Stage 2b: 16 partials + bias -> out ----------------
__global__ __launch_bounds__(256) void reduceB_kernel(
    const float* __restrict__ ws,
    const float* __restrict__ bias,
    float*       __restrict__ out)
{
    int i4 = blockIdx.x * 256 + (int)threadIdx.x;
    const float4* w4 = (const float4*)ws;
    const int stride4 = NNODES / 4;

    float4 acc = ((const float4*)bias)[i4];
    #pragma unroll
    for (int g = 0; g < GROUPS; ++g) {
        float4 t = w4[(size_t)(g * CPG) * stride4 + i4];
        acc.x += t.x; acc.y += t.y; acc.z += t.z; acc.w += t.w;
    }
    ((float4*)out)[i4] = acc;
}

// ---------------- Generic fallback reduce (B != NCOPIES) ----------------
__global__ __launch_bounds__(256) void reduce_generic_kernel(
    const float* __restrict__ ws,
    const float* __restrict__ bias,
    float*       __restrict__ out,
    int B)
{
    int i = blockIdx.x * 256 + (int)threadIdx.x;
    float acc = bias[i];
    for (int cc = 0; cc < B; ++cc) acc += ws[(size_t)cc * NNODES + i];
    out[i] = acc;
}

// ---------------- Fallback: global atomics (tiny ws) ----------------
__global__ __launch_bounds__(256) void init_out_kernel(
    const float* __restrict__ bias, float* __restrict__ out)
{
    int i = blockIdx.x * blockDim.x + threadIdx.x;
    if (i < NNODES) out[i] = bias[i];
}

__global__ __launch_bounds__(256) void edge_atomic_kernel(
    const float* __restrict__ x, const float* __restrict__ w,
    const int* __restrict__ src, const int* __restrict__ dst,
    float* __restrict__ out)
{
    const int n4 = NEDGES / 4;
    int tid = blockIdx.x * blockDim.x + threadIdx.x;
    int stride = gridDim.x * blockDim.x;
    for (int i = tid; i < n4; i += stride) {
        int4 s = ((const int4*)src)[i];
        int4 d = ((const int4*)dst)[i];
        float4 ww = ((const float4*)w)[i];
        atomicAdd(&out[d.x], x[s.x] * ww.x);
        atomicAdd(&out[d.y], x[s.y] * ww.y);
        atomicAdd(&out[d.z], x[s.z] * ww.z);
        atomicAdd(&out[d.w], x[s.w] * ww.w);
    }
}

extern "C" void kernel_launch(void* const* d_in, const int* in_sizes, int n_in,
                              void* d_out, int out_size, void* d_ws, size_t ws_size,
                              hipStream_t stream) {
    const float* x    = (const float*)d_in[0];
    const float* w    = (const float*)d_in[1];
    const float* bias = (const float*)d_in[2];
    const int*   src  = (const int*)d_in[3];
    const int*   dst  = (const int*)d_in[4];
    float* out = (float*)d_out;
    float* ws  = (float*)d_ws;

    const size_t copiesBytes = (size_t)NCOPIES * NNODES * sizeof(float); // 32 MB
    const size_t xLds = (size_t)NNODES * sizeof(_Float16);               // 128 KB

    if (ws_size >= copiesBytes + (size_t)NEDGES * 2) {
        // ---- Preferred: fp16 wx (64 MB ws) ----
        void* wx = (void*)((char*)d_ws + copiesBytes);
        wx_lds_kernel<<<256, THREADS, xLds, stream>>>(x, w, src, wx);
        hist2_kernel<<<NCOPIES * RANGES, THREADS,
                       BINS * sizeof(int), stream>>>(dst, wx, ws, NCOPIES);
        reduceA_kernel<<<GROUPS * (NNODES / 1024), 256, 0, stream>>>(ws);
        reduceB_kernel<<<NNODES / 1024, 256, 0, stream>>>(ws, bias, out);
    } else {
        // ---- Fallback: fused R6 path ----
        size_t copies = ws_size / ((size_t)NNODES * sizeof(float));
        int B = (int)(copies < NCOPIES ? copies : NCOPIES);
        if (B >= 1) {
            hist_kernel<<<B * RANGES, THREADS, BINS * sizeof(float), stream>>>(
                x, w, src, dst, ws, B);
            if (B == NCOPIES) {
                reduceA_kernel<<<GROUPS * (NNODES / 1024), 256, 0, stream>>>(ws);
                reduceB_kernel<<<NNODES / 1024, 256, 0, stream>>>(ws, bias, out);
            } else {
                reduce_generic_kernel<<<NNODES / 256, 256, 0, stream>>>(ws, bias, out, B);
            }
        } else {
            init_out_kernel<<<NNODES / 256, 256, 0, stream>>>(bias, out);
            edge_atomic_kernel<<<4096, 256, 0, stream>>>(x, w, src, dst, out);
        }
    }
}